// Round 16
// baseline (8267.796 us; speedup 1.0000x reference)
//
#include <hip/hip_runtime.h>
#include <math.h>

#define B_ 64
#define T_ 2048
#define D_ 512
#define BT_ (B_ * T_)      // 131072
#define XWORDS (B_ * D_)   // 32768 u64 per parity slot: [quad][k][batch-in-quad]

typedef unsigned long long u64;
typedef float f32x4 __attribute__((ext_vector_type(4)));   // nontemporal-ok

// ---------------------------------------------------------------------------
// Kernel 1: weight prep (transpose to k-major for coalesced GEMM/GEMV reads)
// ---------------------------------------------------------------------------
__global__ void prep_weights(const float* __restrict__ tau_w,
                             const float* __restrict__ mem_w,
                             float* __restrict__ Wcat,
                             float* __restrict__ WTh) {
    int idx = blockIdx.x * 256 + threadIdx.x;   // 0 .. 524287
    {
        int k = idx >> 10, j = idx & 1023;
        float v = (j < 512) ? tau_w[j * 1024 + k] : mem_w[(j - 512) * 512 + k];
        Wcat[idx] = v;
    }
    if (idx < 512 * 512) {
        int k = idx >> 9, d = idx & 511;
        WTh[idx] = tau_w[d * 1024 + 512 + k];
    }
}

// ---------------------------------------------------------------------------
// Kernel 2: f32 GEMM  C[131072][1024] = X[131072][512] @ Wcat[512][1024] + bias
// ---------------------------------------------------------------------------
__global__ __launch_bounds__(256, 2)
void gemm_xw(const float* __restrict__ X, const float* __restrict__ Wc,
             const float* __restrict__ tau_b, const float* __restrict__ mem_b,
             float* __restrict__ Aout, float* __restrict__ Mout) {
    __shared__ __align__(16) float As[16][128];  // [k][m]
    __shared__ __align__(16) float Bs[16][128];  // [k][n]
    const int bn = blockIdx.x;          // 0..7
    const int bm = blockIdx.y;          // 0..1023
    const int tid = threadIdx.x;
    const int tm = (tid >> 4) << 3;
    const int tn = (tid & 15) << 3;
    const int m0 = bm * 128, n0 = bn * 128;

    const float4* X4 = (const float4*)X;
    const float4* Wc4 = (const float4*)Wc;

    float acc[8][8];
#pragma unroll
    for (int i = 0; i < 8; i++)
#pragma unroll
        for (int j = 0; j < 8; j++) acc[i][j] = 0.0f;

    const int ar = tid >> 1;              // 0..127 row in tile
    const int ac2 = (tid & 1) * 2;        // float4 col 0 or 2
    const int bkr = tid >> 4;             // 0..15
    const int bc = (tid & 15) * 2;        // float4 col 0..30

    for (int kt = 0; kt < 512; kt += 16) {
        float4 av0 = X4[(m0 + ar) * 128 + (kt >> 2) + ac2];
        float4 av1 = X4[(m0 + ar) * 128 + (kt >> 2) + ac2 + 1];
        float4 bv0 = Wc4[(kt + bkr) * 256 + bn * 32 + bc];
        float4 bv1 = Wc4[(kt + bkr) * 256 + bn * 32 + bc + 1];
        __syncthreads();   // protect previous iteration's reads
        As[ac2 * 4 + 0][ar] = av0.x;
        As[ac2 * 4 + 1][ar] = av0.y;
        As[ac2 * 4 + 2][ar] = av0.z;
        As[ac2 * 4 + 3][ar] = av0.w;
        As[ac2 * 4 + 4][ar] = av1.x;
        As[ac2 * 4 + 5][ar] = av1.y;
        As[ac2 * 4 + 6][ar] = av1.z;
        As[ac2 * 4 + 7][ar] = av1.w;
        *(float4*)&Bs[bkr][bc * 4] = bv0;
        *(float4*)&Bs[bkr][bc * 4 + 4] = bv1;
        __syncthreads();
#pragma unroll
        for (int kk = 0; kk < 16; kk++) {
            float4 a0 = *(const float4*)&As[kk][tm];
            float4 a1 = *(const float4*)&As[kk][tm + 4];
            float4 b0 = *(const float4*)&Bs[kk][tn];
            float4 b1 = *(const float4*)&Bs[kk][tn + 4];
            float av[8] = {a0.x, a0.y, a0.z, a0.w, a1.x, a1.y, a1.z, a1.w};
            float bv[8] = {b0.x, b0.y, b0.z, b0.w, b1.x, b1.y, b1.z, b1.w};
#pragma unroll
            for (int i = 0; i < 8; i++)
#pragma unroll
                for (int j = 0; j < 8; j++)
                    acc[i][j] = fmaf(av[i], bv[j], acc[i][j]);
        }
    }

    const bool isA = (bn < 4);
    float* Cout = isA ? Aout : Mout;
    const float* bias = isA ? tau_b : mem_b;
    const int ncol0 = (isA ? n0 : n0 - 512) + tn;
    float bj[8];
#pragma unroll
    for (int j = 0; j < 8; j++) bj[j] = bias[ncol0 + j];
#pragma unroll
    for (int i = 0; i < 8; i++) {
        size_t off = (size_t)(m0 + tm + i) * 512 + ncol0;
        f32x4 o0, o1;
        o0.x = acc[i][0] + bj[0]; o0.y = acc[i][1] + bj[1];
        o0.z = acc[i][2] + bj[2]; o0.w = acc[i][3] + bj[3];
        o1.x = acc[i][4] + bj[4]; o1.y = acc[i][5] + bj[5];
        o1.z = acc[i][6] + bj[6]; o1.w = acc[i][7] + bj[7];
        __builtin_nontemporal_store(o0, (f32x4*)&Cout[off]);
        __builtin_nontemporal_store(o1, (f32x4*)&Cout[off + 4]);
    }
}

// ---------------------------------------------------------------------------
// Kernel 3: reset sync state every launch (graph-replay safe).
// Slot0 words = {seq=0, tau=1.0} (the t=0 carry); slot1 words = {seq=0, *}.
// ---------------------------------------------------------------------------
__global__ void init_sync(u64* __restrict__ xchg, int* __restrict__ ctr) {
    int idx = blockIdx.x * 256 + threadIdx.x;   // 0 .. 65535
    if (idx < 2 * XWORDS) xchg[idx] = (idx < XWORDS) ? 0x3F800000ull : 0ull;
    if (idx < 16) ctr[idx] = 0;
}

// ---------------------------------------------------------------------------
// Kernel 4: cooperative scan — round-16 "quad-batch" restructure of r8 (the
// 4.10ms champion). 256 blocks = 16 channel-segments (32 ch) x 16 batch-
// quads (4 batches). Weight slice = 512x32 = 64KB LDS, read ONCE per step
// (~512 cyc on the LDS pipe vs r8's 2048 for 128KB) — each weight feeds 4
// batches. FMA/thread unchanged (128). tau via r8's cheap uniform-address
// LDS broadcasts (readlane was r10/r12's regression: 2x VALU). Poll: wave
// ws owns k-window [ws*64,+64) = segments {2ws,2ws+1}; lane polls 4
// ADJACENT u64 (one 32B line: 4 batches of its k) — co-XCD publishers via
// XCC_ID role mapping (rank&15=seg, quad=xcd*2+rank>>4). Publish-early
// epilogue; 2 barriers (r8-proven); 16-slot k-ascending fold bit-identical
// to r8. Agent-scope atomics (only proven-visible primitive, r13/r14).
// ---------------------------------------------------------------------------
__global__ __launch_bounds__(512)
__attribute__((amdgpu_waves_per_eu(2, 2)))
void scan_q4(const float* __restrict__ WTh,
             const float* __restrict__ Mm,
             const float* __restrict__ log_thresh,
             float* __restrict__ AmOut,   // A in / spikes out (d_out)
             float* __restrict__ OutTail, // d_out base for tau/v tails
             u64* __restrict__ xchg,
             int* __restrict__ ctr) {
    __shared__ __align__(16) float4 w_lds[4096];     // 64 KB [(k>>2)*32+ch]
    __shared__ __align__(16) float tau_s[4][512];    // 8 KB  [b][k]
    __shared__ __align__(16) float part[4][16][32];  // 8 KB  [b][slot][ch]
    __shared__ float pad_lds[10240];                 // 40 KB occupancy pad
    __shared__ int role_s;

    const int tid = threadIdx.x;

    if (tid == 0) {
        unsigned xcd;
        asm volatile("s_getreg_b32 %0, hwreg(HW_REG_XCC_ID)" : "=s"(xcd));
        xcd &= 7;
        int rank = atomicAdd(&ctr[xcd], 1) & 31;
        role_s = ((rank & 15) << 8) | ((int)xcd * 2 + (rank >> 4));
    }
    __syncthreads();
    const int sg = role_s >> 8;    // channel segment 0..15 (32 channels)
    const int qd = role_s & 255;   // batch quad 0..15 (4 batches)
    // opaque never-true runtime condition keeps the pad allocated
    if (role_s == -12345) pad_lds[tid] = 1.f;

    // ---- stage weight slice into LDS (one-time, 64 KB) ----
    {
        const int ch = tid & 31;
        const int kr = tid >> 5;           // 0..15
        float* wl = (float*)w_lds;
        for (int i = 0; i < 32; i++) {
            int krow = i * 16 + kr;
            wl[(krow >> 2) * 128 + ch * 4 + (krow & 3)] =
                WTh[krow * 512 + sg * 32 + ch];
        }
    }

    const int ws = tid >> 6;       // wave: k-window [ws*64, ws*64+64)
    const int lane = tid & 63;
    const int cp = lane & 31;      // channel within segment
    const int kh = lane >> 5;      // k-half of the window

    // epilogue identity (tid < 128): channel ech, batch-in-quad eb
    const int ech = tid & 31;
    const int eb = (tid >> 5) & 3;
    const int gch = sg * 32 + ech;           // global channel (= k for readers)
    const int batch = qd * 4 + eb;
    float thr = 0.f, v = 0.f, tk = 1.0f;
    if (tid < 128) thr = 1.0f / (1.0f + expf(-log_thresh[gch]));
    size_t abase = (size_t)batch * T_ * D_ + gch;

    // prime the A/M software pipeline (step 1's values) — nontemporal
    float a_pf = 0.f, m_pf = 0.f;
    if (tid < 128) {
        a_pf = __builtin_nontemporal_load(&AmOut[abase]);
        m_pf = __builtin_nontemporal_load(&Mm[abase]);
    }
    __syncthreads();   // weights staged

    for (int c = 1; c <= T_; c++) {
        // issue next step's A/M loads (consumed next iteration's epilogue)
        float a_nx = 0.f, m_nx = 0.f;
        if (tid < 128) {
            size_t nx = (c < T_) ? abase + D_ : abase;
            a_nx = __builtin_nontemporal_load(&AmOut[nx]);
            m_nx = __builtin_nontemporal_load(&Mm[nx]);
        }

        // ---- poll: lane's k = ws*64+lane; 4 adjacent words (one line) ----
        const u64* s = xchg + (size_t)((c - 1) & 1) * XWORDS
                            + (size_t)qd * 2048 + (size_t)(ws * 64 + lane) * 4;
        const unsigned tgt = (unsigned)(c - 1);
        u64 w0, w1, w2, w3;
        int guard = 0;
        do {
            w0 = __hip_atomic_load(s + 0, __ATOMIC_RELAXED,
                                   __HIP_MEMORY_SCOPE_AGENT);
            w1 = __hip_atomic_load(s + 1, __ATOMIC_RELAXED,
                                   __HIP_MEMORY_SCOPE_AGENT);
            w2 = __hip_atomic_load(s + 2, __ATOMIC_RELAXED,
                                   __HIP_MEMORY_SCOPE_AGENT);
            w3 = __hip_atomic_load(s + 3, __ATOMIC_RELAXED,
                                   __HIP_MEMORY_SCOPE_AGENT);
        } while ((((unsigned)(w0 >> 32) < tgt) |
                  ((unsigned)(w1 >> 32) < tgt) |
                  ((unsigned)(w2 >> 32) < tgt) |
                  ((unsigned)(w3 >> 32) < tgt)) && ++guard < (1 << 20));
        tau_s[0][ws * 64 + lane] = __uint_as_float((unsigned)w0);
        tau_s[1][ws * 64 + lane] = __uint_as_float((unsigned)w1);
        tau_s[2][ws * 64 + lane] = __uint_as_float((unsigned)w2);
        tau_s[3][ws * 64 + lane] = __uint_as_float((unsigned)w3);
        __builtin_amdgcn_wave_barrier();   // wave-private strip: no block sync

        // ---- FMA: 1 channel x 4 batches over 32-k half-window ----
        float acc0 = 0.f, acc1 = 0.f, acc2 = 0.f, acc3 = 0.f;
#pragma unroll
        for (int q = 0; q < 8; q++) {
            const int qq = ws * 16 + kh * 8 + q;
            float4 wv = w_lds[qq * 32 + cp];
            const int k0 = ws * 64 + kh * 32 + q * 4;
            float4 t0 = *(const float4*)&tau_s[0][k0];
            float4 t1 = *(const float4*)&tau_s[1][k0];
            float4 t2 = *(const float4*)&tau_s[2][k0];
            float4 t3 = *(const float4*)&tau_s[3][k0];
            acc0 = fmaf(t0.x, wv.x, acc0); acc0 = fmaf(t0.y, wv.y, acc0);
            acc0 = fmaf(t0.z, wv.z, acc0); acc0 = fmaf(t0.w, wv.w, acc0);
            acc1 = fmaf(t1.x, wv.x, acc1); acc1 = fmaf(t1.y, wv.y, acc1);
            acc1 = fmaf(t1.z, wv.z, acc1); acc1 = fmaf(t1.w, wv.w, acc1);
            acc2 = fmaf(t2.x, wv.x, acc2); acc2 = fmaf(t2.y, wv.y, acc2);
            acc2 = fmaf(t2.z, wv.z, acc2); acc2 = fmaf(t2.w, wv.w, acc2);
            acc3 = fmaf(t3.x, wv.x, acc3); acc3 = fmaf(t3.y, wv.y, acc3);
            acc3 = fmaf(t3.z, wv.z, acc3); acc3 = fmaf(t3.w, wv.w, acc3);
        }
        const int slot = ws * 2 + kh;      // k-ascending slot order
        part[0][slot][cp] = acc0;
        part[1][slot][cp] = acc1;
        part[2][slot][cp] = acc2;
        part[3][slot][cp] = acc3;
        __syncthreads();   // A: all 16 partial slots ready

        // ---- epilogue on 128 threads; publish FIRST, tail after ----
        if (tid < 128) {
            float sum = 0.f;
#pragma unroll
            for (int j = 0; j < 16; j++) sum += part[eb][j][ech];
            float pre = sum + a_pf;
            float tau = 1.0f / (1.0f + expf(-pre));
            u64 pack = ((u64)(unsigned)c << 32) | (u64)__float_as_uint(tau);
            __hip_atomic_store(&xchg[(size_t)(c & 1) * XWORDS
                                     + (size_t)qd * 2048 + (size_t)gch * 4 + eb],
                               pack, __ATOMIC_RELAXED, __HIP_MEMORY_SCOPE_AGENT);
            // off-critical-path tail
            float alpha = expf(-1.0f / (tau + 1e-6f));
            v = alpha * v + (1.0f - alpha) * m_pf;
            float sp = (v >= thr) ? 1.0f : 0.0f;
            __builtin_nontemporal_store(sp, &AmOut[abase]);  // spike out
            v = v * (1.0f - sp);
            tk = tau;
            abase += D_;
            a_pf = a_nx; m_pf = m_nx;    // advance the pipeline
        }
        __syncthreads();   // B: part[] reusable next step
    }

    if (tid < 128) {
        OutTail[(size_t)BT_ * D_ + (size_t)batch * D_ + gch] = tk;
        OutTail[(size_t)BT_ * D_ + (size_t)B_ * D_ + (size_t)batch * D_ + gch] = v;
    }
}

// ---------------------------------------------------------------------------
extern "C" void kernel_launch(void* const* d_in, const int* in_sizes, int n_in,
                              void* d_out, int out_size, void* d_ws, size_t ws_size,
                              hipStream_t stream) {
    (void)in_sizes; (void)n_in; (void)out_size; (void)ws_size;
    const float* x          = (const float*)d_in[0];
    const float* tau_w      = (const float*)d_in[1];
    const float* tau_b      = (const float*)d_in[2];
    const float* mem_w      = (const float*)d_in[3];
    const float* mem_b      = (const float*)d_in[4];
    const float* log_thresh = (const float*)d_in[5];
    float* out = (float*)d_out;

    // workspace layout
    float* Wcat = (float*)d_ws;            // 512*1024 (dead after GEMM)
    float* WTh  = Wcat + 512 * 1024;       // 512*512
    float* Mout = WTh + 512 * 512;         // 131072*512
    // sync state reuses the Wcat region (GEMM finishes before init_sync)
    u64* xchg = (u64*)d_ws;                           // 2*XWORDS*8 = 512 KB
    int* ctr  = (int*)((char*)d_ws + 2 * XWORDS * sizeof(u64));

    float* Aout = out;                     // spikes region doubles as A buffer

    prep_weights<<<2048, 256, 0, stream>>>(tau_w, mem_w, Wcat, WTh);
    gemm_xw<<<dim3(8, 1024), 256, 0, stream>>>(x, Wcat, tau_b, mem_b, Aout, Mout);
    init_sync<<<256, 256, 0, stream>>>(xchg, ctr);

    const float* WThc = WTh;
    const float* Mmc  = Mout;
    const float* ltc  = log_thresh;
    float* outp = out;
    u64* xchgp = xchg;
    int* ctrp = ctr;
    void* args[7] = {(void*)&WThc, (void*)&Mmc, (void*)&ltc,
                     (void*)&Aout, (void*)&outp, (void*)&xchgp, (void*)&ctrp};
    hipLaunchCooperativeKernel((const void*)scan_q4, dim3(256), dim3(512),
                               args, 0, stream);
}

// Round 17
// 6744.608 us; speedup vs baseline: 1.2258x; 1.2258x over previous
//
#include <hip/hip_runtime.h>
#include <math.h>

#define B_ 64
#define T_ 2048
#define D_ 512
#define BT_ (B_ * T_)      // 131072
#define XWORDS (B_ * D_)   // 32768 u64 per parity slot: [batch][k]

typedef unsigned long long u64;
typedef float f32x4 __attribute__((ext_vector_type(4)));   // nontemporal-ok

// ---------------------------------------------------------------------------
// Kernel 1: weight prep (transpose to k-major for coalesced GEMM/GEMV reads)
// ---------------------------------------------------------------------------
__global__ void prep_weights(const float* __restrict__ tau_w,
                             const float* __restrict__ mem_w,
                             float* __restrict__ Wcat,
                             float* __restrict__ WTh) {
    int idx = blockIdx.x * 256 + threadIdx.x;   // 0 .. 524287
    {
        int k = idx >> 10, j = idx & 1023;
        float v = (j < 512) ? tau_w[j * 1024 + k] : mem_w[(j - 512) * 512 + k];
        Wcat[idx] = v;
    }
    if (idx < 512 * 512) {
        int k = idx >> 9, d = idx & 511;
        WTh[idx] = tau_w[d * 1024 + 512 + k];
    }
}

// ---------------------------------------------------------------------------
// Kernel 2: f32 GEMM  C[131072][1024] = X[131072][512] @ Wcat[512][1024] + bias
// ---------------------------------------------------------------------------
__global__ __launch_bounds__(256, 2)
void gemm_xw(const float* __restrict__ X, const float* __restrict__ Wc,
             const float* __restrict__ tau_b, const float* __restrict__ mem_b,
             float* __restrict__ Aout, float* __restrict__ Mout) {
    __shared__ __align__(16) float As[16][128];  // [k][m]
    __shared__ __align__(16) float Bs[16][128];  // [k][n]
    const int bn = blockIdx.x;          // 0..7
    const int bm = blockIdx.y;          // 0..1023
    const int tid = threadIdx.x;
    const int tm = (tid >> 4) << 3;
    const int tn = (tid & 15) << 3;
    const int m0 = bm * 128, n0 = bn * 128;

    const float4* X4 = (const float4*)X;
    const float4* Wc4 = (const float4*)Wc;

    float acc[8][8];
#pragma unroll
    for (int i = 0; i < 8; i++)
#pragma unroll
        for (int j = 0; j < 8; j++) acc[i][j] = 0.0f;

    const int ar = tid >> 1;              // 0..127 row in tile
    const int ac2 = (tid & 1) * 2;        // float4 col 0 or 2
    const int bkr = tid >> 4;             // 0..15
    const int bc = (tid & 15) * 2;        // float4 col 0..30

    for (int kt = 0; kt < 512; kt += 16) {
        float4 av0 = X4[(m0 + ar) * 128 + (kt >> 2) + ac2];
        float4 av1 = X4[(m0 + ar) * 128 + (kt >> 2) + ac2 + 1];
        float4 bv0 = Wc4[(kt + bkr) * 256 + bn * 32 + bc];
        float4 bv1 = Wc4[(kt + bkr) * 256 + bn * 32 + bc + 1];
        __syncthreads();   // protect previous iteration's reads
        As[ac2 * 4 + 0][ar] = av0.x;
        As[ac2 * 4 + 1][ar] = av0.y;
        As[ac2 * 4 + 2][ar] = av0.z;
        As[ac2 * 4 + 3][ar] = av0.w;
        As[ac2 * 4 + 4][ar] = av1.x;
        As[ac2 * 4 + 5][ar] = av1.y;
        As[ac2 * 4 + 6][ar] = av1.z;
        As[ac2 * 4 + 7][ar] = av1.w;
        *(float4*)&Bs[bkr][bc * 4] = bv0;
        *(float4*)&Bs[bkr][bc * 4 + 4] = bv1;
        __syncthreads();
#pragma unroll
        for (int kk = 0; kk < 16; kk++) {
            float4 a0 = *(const float4*)&As[kk][tm];
            float4 a1 = *(const float4*)&As[kk][tm + 4];
            float4 b0 = *(const float4*)&Bs[kk][tn];
            float4 b1 = *(const float4*)&Bs[kk][tn + 4];
            float av[8] = {a0.x, a0.y, a0.z, a0.w, a1.x, a1.y, a1.z, a1.w};
            float bv[8] = {b0.x, b0.y, b0.z, b0.w, b1.x, b1.y, b1.z, b1.w};
#pragma unroll
            for (int i = 0; i < 8; i++)
#pragma unroll
                for (int j = 0; j < 8; j++)
                    acc[i][j] = fmaf(av[i], bv[j], acc[i][j]);
        }
    }

    const bool isA = (bn < 4);
    float* Cout = isA ? Aout : Mout;
    const float* bias = isA ? tau_b : mem_b;
    const int ncol0 = (isA ? n0 : n0 - 512) + tn;
    float bj[8];
#pragma unroll
    for (int j = 0; j < 8; j++) bj[j] = bias[ncol0 + j];
#pragma unroll
    for (int i = 0; i < 8; i++) {
        size_t off = (size_t)(m0 + tm + i) * 512 + ncol0;
        f32x4 o0, o1;
        o0.x = acc[i][0] + bj[0]; o0.y = acc[i][1] + bj[1];
        o0.z = acc[i][2] + bj[2]; o0.w = acc[i][3] + bj[3];
        o1.x = acc[i][4] + bj[4]; o1.y = acc[i][5] + bj[5];
        o1.z = acc[i][6] + bj[6]; o1.w = acc[i][7] + bj[7];
        __builtin_nontemporal_store(o0, (f32x4*)&Cout[off]);
        __builtin_nontemporal_store(o1, (f32x4*)&Cout[off + 4]);
    }
}

// ---------------------------------------------------------------------------
// Kernel 3: reset sync state every launch (graph-replay safe).
// Slot0 words = {seq=0, tau=1.0} (the t=0 carry); slot1 words = {seq=0, *}.
// ---------------------------------------------------------------------------
__global__ void init_sync(u64* __restrict__ xchg, int* __restrict__ ctr) {
    int idx = blockIdx.x * 256 + threadIdx.x;   // 0 .. 65535
    if (idx < 2 * XWORDS) xchg[idx] = (idx < XWORDS) ? 0x3F800000ull : 0ull;
    if (idx < 16) ctr[idx] = 0;
}

// ---------------------------------------------------------------------------
// Kernel 4: cooperative scan — r16's quad-batch compute + r8's COALESCED
// exchange layout (round-17 fix).
//
// r16 diagnosis: [k][batch]-interleaved publishes made each 8B agent-atomic
// store stride-32B -> uncoalesced write granules at the coherence point ->
// WRITE_SIZE 787->1311MB and 3.3us/step. Fix: xchg back to [par][batch][k]
// (r8/r12 layout): publish = 32 consecutive lanes write 32 consecutive u64
// (256B contiguous); poll = 4 batch-strided full-wave coalesced loads,
// issued together (visibility latency paid once).
// Compute structure unchanged from r16 (passed, absmax 2.38e-7):
// 16 segments x 16 quads, 64KB weight slice read once/step, 4-batch FMA,
// k-ascending 16-slot fold, publish-early epilogue, 2 barriers.
// ---------------------------------------------------------------------------
__global__ __launch_bounds__(512)
__attribute__((amdgpu_waves_per_eu(2, 2)))
void scan_q4c(const float* __restrict__ WTh,
              const float* __restrict__ Mm,
              const float* __restrict__ log_thresh,
              float* __restrict__ AmOut,   // A in / spikes out (d_out)
              float* __restrict__ OutTail, // d_out base for tau/v tails
              u64* __restrict__ xchg,
              int* __restrict__ ctr) {
    __shared__ __align__(16) float4 w_lds[4096];     // 64 KB [(k>>2)*32+ch]
    __shared__ __align__(16) float tau_s[4][512];    // 8 KB  [b][k]
    __shared__ __align__(16) float part[4][16][32];  // 8 KB  [b][slot][ch]
    __shared__ float pad_lds[10240];                 // occupancy pad
    __shared__ int role_s;

    const int tid = threadIdx.x;

    if (tid == 0) {
        unsigned xcd;
        asm volatile("s_getreg_b32 %0, hwreg(HW_REG_XCC_ID)" : "=s"(xcd));
        xcd &= 7;
        int rank = atomicAdd(&ctr[xcd], 1) & 31;
        role_s = ((rank & 15) << 8) | ((int)xcd * 2 + (rank >> 4));
    }
    __syncthreads();
    const int sg = role_s >> 8;    // channel segment 0..15 (32 channels)
    const int qd = role_s & 255;   // batch quad 0..15 (4 batches)
    if (role_s == -12345) pad_lds[tid] = 1.f;   // keep pad allocated

    // ---- stage weight slice into LDS (one-time, 64 KB) ----
    {
        const int ch = tid & 31;
        const int kr = tid >> 5;           // 0..15
        float* wl = (float*)w_lds;
        for (int i = 0; i < 32; i++) {
            int krow = i * 16 + kr;
            wl[(krow >> 2) * 128 + ch * 4 + (krow & 3)] =
                WTh[krow * 512 + sg * 32 + ch];
        }
    }

    const int ws = tid >> 6;       // wave: k-window [ws*64, ws*64+64)
    const int lane = tid & 63;
    const int cp = lane & 31;      // channel within segment
    const int kh = lane >> 5;      // k-half of the window

    // epilogue identity (tid < 128): channel ech, batch-in-quad eb
    const int ech = tid & 31;
    const int eb = (tid >> 5) & 3;
    const int gch = sg * 32 + ech;           // global channel
    const int batch = qd * 4 + eb;
    float thr = 0.f, v = 0.f, tk = 1.0f;
    if (tid < 128) thr = 1.0f / (1.0f + expf(-log_thresh[gch]));
    size_t abase = (size_t)batch * T_ * D_ + gch;

    // prime the A/M software pipeline (step 1's values) — nontemporal
    float a_pf = 0.f, m_pf = 0.f;
    if (tid < 128) {
        a_pf = __builtin_nontemporal_load(&AmOut[abase]);
        m_pf = __builtin_nontemporal_load(&Mm[abase]);
    }
    __syncthreads();   // weights staged

    for (int c = 1; c <= T_; c++) {
        // issue next step's A/M loads (consumed next iteration's epilogue)
        float a_nx = 0.f, m_nx = 0.f;
        if (tid < 128) {
            size_t nx = (c < T_) ? abase + D_ : abase;
            a_nx = __builtin_nontemporal_load(&AmOut[nx]);
            m_nx = __builtin_nontemporal_load(&Mm[nx]);
        }

        // ---- poll: 4 batch-strided COALESCED loads of k = ws*64+lane ----
        const u64* sb = xchg + (size_t)((c - 1) & 1) * XWORDS
                             + (size_t)(qd * 4) * 512 + ws * 64 + lane;
        const unsigned tgt = (unsigned)(c - 1);
        u64 w0, w1, w2, w3;
        int guard = 0;
        do {
            w0 = __hip_atomic_load(sb,        __ATOMIC_RELAXED,
                                   __HIP_MEMORY_SCOPE_AGENT);
            w1 = __hip_atomic_load(sb + 512,  __ATOMIC_RELAXED,
                                   __HIP_MEMORY_SCOPE_AGENT);
            w2 = __hip_atomic_load(sb + 1024, __ATOMIC_RELAXED,
                                   __HIP_MEMORY_SCOPE_AGENT);
            w3 = __hip_atomic_load(sb + 1536, __ATOMIC_RELAXED,
                                   __HIP_MEMORY_SCOPE_AGENT);
        } while ((((unsigned)(w0 >> 32) < tgt) |
                  ((unsigned)(w1 >> 32) < tgt) |
                  ((unsigned)(w2 >> 32) < tgt) |
                  ((unsigned)(w3 >> 32) < tgt)) && ++guard < (1 << 20));
        tau_s[0][ws * 64 + lane] = __uint_as_float((unsigned)w0);
        tau_s[1][ws * 64 + lane] = __uint_as_float((unsigned)w1);
        tau_s[2][ws * 64 + lane] = __uint_as_float((unsigned)w2);
        tau_s[3][ws * 64 + lane] = __uint_as_float((unsigned)w3);
        __builtin_amdgcn_wave_barrier();   // wave-private strip: no block sync

        // ---- FMA: 1 channel x 4 batches over 32-k half-window ----
        float acc0 = 0.f, acc1 = 0.f, acc2 = 0.f, acc3 = 0.f;
#pragma unroll
        for (int q = 0; q < 8; q++) {
            const int qq = ws * 16 + kh * 8 + q;
            float4 wv = w_lds[qq * 32 + cp];
            const int k0 = ws * 64 + kh * 32 + q * 4;
            float4 t0 = *(const float4*)&tau_s[0][k0];
            float4 t1 = *(const float4*)&tau_s[1][k0];
            float4 t2 = *(const float4*)&tau_s[2][k0];
            float4 t3 = *(const float4*)&tau_s[3][k0];
            acc0 = fmaf(t0.x, wv.x, acc0); acc0 = fmaf(t0.y, wv.y, acc0);
            acc0 = fmaf(t0.z, wv.z, acc0); acc0 = fmaf(t0.w, wv.w, acc0);
            acc1 = fmaf(t1.x, wv.x, acc1); acc1 = fmaf(t1.y, wv.y, acc1);
            acc1 = fmaf(t1.z, wv.z, acc1); acc1 = fmaf(t1.w, wv.w, acc1);
            acc2 = fmaf(t2.x, wv.x, acc2); acc2 = fmaf(t2.y, wv.y, acc2);
            acc2 = fmaf(t2.z, wv.z, acc2); acc2 = fmaf(t2.w, wv.w, acc2);
            acc3 = fmaf(t3.x, wv.x, acc3); acc3 = fmaf(t3.y, wv.y, acc3);
            acc3 = fmaf(t3.z, wv.z, acc3); acc3 = fmaf(t3.w, wv.w, acc3);
        }
        const int slot = ws * 2 + kh;      // k-ascending slot order
        part[0][slot][cp] = acc0;
        part[1][slot][cp] = acc1;
        part[2][slot][cp] = acc2;
        part[3][slot][cp] = acc3;
        __syncthreads();   // A: all 16 partial slots ready

        // ---- epilogue on 128 threads; publish FIRST (coalesced), tail after
        if (tid < 128) {
            float sum = 0.f;
#pragma unroll
            for (int j = 0; j < 16; j++) sum += part[eb][j][ech];
            float pre = sum + a_pf;
            float tau = 1.0f / (1.0f + expf(-pre));
            u64 pack = ((u64)(unsigned)c << 32) | (u64)__float_as_uint(tau);
            __hip_atomic_store(&xchg[(size_t)(c & 1) * XWORDS
                                     + (size_t)batch * 512 + gch],
                               pack, __ATOMIC_RELAXED, __HIP_MEMORY_SCOPE_AGENT);
            // off-critical-path tail
            float alpha = expf(-1.0f / (tau + 1e-6f));
            v = alpha * v + (1.0f - alpha) * m_pf;
            float sp = (v >= thr) ? 1.0f : 0.0f;
            __builtin_nontemporal_store(sp, &AmOut[abase]);  // spike out
            v = v * (1.0f - sp);
            tk = tau;
            abase += D_;
            a_pf = a_nx; m_pf = m_nx;    // advance the pipeline
        }
        __syncthreads();   // B: part[] reusable next step
    }

    if (tid < 128) {
        OutTail[(size_t)BT_ * D_ + (size_t)batch * D_ + gch] = tk;
        OutTail[(size_t)BT_ * D_ + (size_t)B_ * D_ + (size_t)batch * D_ + gch] = v;
    }
}

// ---------------------------------------------------------------------------
extern "C" void kernel_launch(void* const* d_in, const int* in_sizes, int n_in,
                              void* d_out, int out_size, void* d_ws, size_t ws_size,
                              hipStream_t stream) {
    (void)in_sizes; (void)n_in; (void)out_size; (void)ws_size;
    const float* x          = (const float*)d_in[0];
    const float* tau_w      = (const float*)d_in[1];
    const float* tau_b      = (const float*)d_in[2];
    const float* mem_w      = (const float*)d_in[3];
    const float* mem_b      = (const float*)d_in[4];
    const float* log_thresh = (const float*)d_in[5];
    float* out = (float*)d_out;

    // workspace layout
    float* Wcat = (float*)d_ws;            // 512*1024 (dead after GEMM)
    float* WTh  = Wcat + 512 * 1024;       // 512*512
    float* Mout = WTh + 512 * 512;         // 131072*512
    // sync state reuses the Wcat region (GEMM finishes before init_sync)
    u64* xchg = (u64*)d_ws;                           // 2*XWORDS*8 = 512 KB
    int* ctr  = (int*)((char*)d_ws + 2 * XWORDS * sizeof(u64));

    float* Aout = out;                     // spikes region doubles as A buffer

    prep_weights<<<2048, 256, 0, stream>>>(tau_w, mem_w, Wcat, WTh);
    gemm_xw<<<dim3(8, 1024), 256, 0, stream>>>(x, Wcat, tau_b, mem_b, Aout, Mout);
    init_sync<<<256, 256, 0, stream>>>(xchg, ctr);

    const float* WThc = WTh;
    const float* Mmc  = Mout;
    const float* ltc  = log_thresh;
    float* outp = out;
    u64* xchgp = xchg;
    int* ctrp = ctr;
    void* args[7] = {(void*)&WThc, (void*)&Mmc, (void*)&ltc,
                     (void*)&Aout, (void*)&outp, (void*)&xchgp, (void*)&ctrp};
    hipLaunchCooperativeKernel((const void*)scan_q4c, dim3(256), dim3(512),
                               args, 0, stream);
}